// Round 1
// 12307.354 us; speedup vs baseline: 1.3673x; 1.3673x over previous
//
#include <hip/hip_runtime.h>
#include <stdint.h>

#define Bsz 64
#define Tsz 1024
#define NIc 128
#define NHc 512
#define DTc 0.1f
#define NWG 32
#define JW  16
#define FLG 16   // flag stride in ints (64B apart)

typedef __attribute__((ext_vector_type(8))) short short8;
typedef __attribute__((ext_vector_type(4))) float f32x4;
typedef unsigned long long u64_t;

__device__ __forceinline__ unsigned short f2bf(float f) {
  union { float f; uint32_t u; } v; v.f = f;
  return (unsigned short)((v.u + 0x7fffu + ((v.u >> 16) & 1u)) >> 16);
}
__device__ __forceinline__ float bf2f(unsigned short h) {
  union { float f; uint32_t u; } v; v.u = ((uint32_t)h) << 16; return v.f;
}
__device__ __forceinline__ float fast_tanh(float xx) {
  float a = __builtin_fabsf(xx);
  float e = __expf(-2.0f * a);
  float r = (1.0f - e) / (1.0f + e);
  return __builtin_copysignf(r, xx);
}

// ---- fenced barrier helpers: used ONCE (prologue handoff of plain cached stores) ----
__device__ __forceinline__ void wait_flags(int* flags, int target, int tid) {
  if (tid < NWG) {
    while (__hip_atomic_load(&flags[tid * FLG], __ATOMIC_RELAXED,
                             __HIP_MEMORY_SCOPE_AGENT) < target)
      __builtin_amdgcn_s_sleep(1);
  }
  __syncthreads();
  __builtin_amdgcn_fence(__ATOMIC_ACQUIRE, "agent");
}
__device__ __forceinline__ void publish_flag(int* flags, int g, int val, int tid) {
  __builtin_amdgcn_fence(__ATOMIC_RELEASE, "agent");
  __syncthreads();
  if (tid == 0)
    __hip_atomic_store(&flags[g * FLG], val, __ATOMIC_RELAXED,
                       __HIP_MEMORY_SCOPE_AGENT);
}

// ---- fence-free exchange (recurrent loop) ----
// Waits: poll flags with relaxed agent atomics only. No acquire fence — consumers
// read the data through sc0/sc1 atomics, so L1/L2 staleness is irrelevant and the
// rest of the kernel's cached state (u-prefetch, out lines) survives.
__device__ __forceinline__ void wait_nf(int* flags, int target, int tid) {
  if (tid < NWG) {
    while (__hip_atomic_load(&flags[tid * FLG], __ATOMIC_RELAXED,
                             __HIP_MEMORY_SCOPE_AGENT) < target)
      __builtin_amdgcn_s_sleep(1);
  }
  __syncthreads();
}
// Publish: LDS-bounced slice -> 256 x u64 write-through (sc0 sc1) atomic stores ->
// per-wave vmcnt(0) drain -> barrier -> flag store. No buffer_wbl2.
__device__ __forceinline__ void publish_nf(unsigned short* dst /*[64][512]*/,
                                           const unsigned short* bnc /*[64][16]*/,
                                           int J0, int* flag_addr, int val, int tid) {
  __syncthreads();  // bounce tile complete
  {
    const u64_t v = ((const u64_t*)bnc)[tid];
    const int row = tid >> 2, q = tid & 3;
    __hip_atomic_store((u64_t*)(dst + row * NHc + J0 + q * 4), v,
                       __ATOMIC_RELAXED, __HIP_MEMORY_SCOPE_AGENT);
  }
  asm volatile("s_waitcnt vmcnt(0)" ::: "memory");  // this wave's stores at coherence point
  __syncthreads();                                  // all waves drained
  if (tid == 0)
    __hip_atomic_store(flag_addr, val, __ATOMIC_RELAXED, __HIP_MEMORY_SCOPE_AGENT);
}
// Consumer A-fragment: 16B as two u64 relaxed agent loads (global_load_dwordx2 sc0 sc1)
__device__ __forceinline__ short8 ld_frag(const u64_t* base64, int idx64) {
  union { u64_t q[2]; short8 s; } u;
  u.q[0] = __hip_atomic_load(base64 + idx64, __ATOMIC_RELAXED, __HIP_MEMORY_SCOPE_AGENT);
  u.q[1] = __hip_atomic_load(base64 + idx64 + 1, __ATOMIC_RELAXED, __HIP_MEMORY_SCOPE_AGENT);
  return u.s;
}

__global__ __launch_bounds__(256, 1)
void pirn_kernel(const float* __restrict__ x, const float* __restrict__ x2h,
                 const float* __restrict__ h2h, const float* __restrict__ bias,
                 const float* __restrict__ gam_p, const float* __restrict__ eps_p,
                 float* __restrict__ out, char* __restrict__ ws)
{
  __shared__ __align__(16) char lds[35328];
  const int g    = blockIdx.x;
  const int tid  = threadIdx.x;
  const int lane = tid & 63;
  const int wv   = tid >> 6;
  const int l15  = lane & 15;
  const int quad = lane >> 4;

  int* hyflag   = (int*)ws;
  int* preflag  = (int*)(ws + 2048);
  int* prolflag = (int*)(ws + 4096);
  unsigned short* hybuf  = (unsigned short*)(ws + 8192);            // [2][64][512] bf16
  unsigned short* prebuf = (unsigned short*)(ws + 8192 + 131072);   // [2][64][512] bf16

  // ---------------- prologue: out[b,t,:] = tanh(x[b,t,:] @ x2h) ----------------
  // WG g owns rows [g*2048, (g+1)*2048) of the (B*T, H) problem (= batches 2g,2g+1).
  {
    unsigned short* x2ht_hi = (unsigned short*)lds;             // [64][136]
    unsigned short* x2ht_lo = (unsigned short*)(lds + 17408);   // [64][136]
    const long R0 = (long)g * 2048;
    for (int pass = 0; pass < 8; ++pass) {
      const int c0 = pass * 64;
      __syncthreads();
      for (int i = tid; i < 64 * NIc; i += 256) {
        int c = i & 63; int k = i >> 6;
        float v = x2h[k * NHc + c0 + c];
        unsigned short hi = f2bf(v);
        x2ht_hi[c * 136 + k] = hi;
        x2ht_lo[c * 136 + k] = f2bf(v - bf2f(hi));
      }
      __syncthreads();
      for (int mt = wv * 32; mt < wv * 32 + 32; ++mt) {
        const float* xr = x + (R0 + mt * 16 + l15) * NIc;
        short8 ahi[4], alo[4];
#pragma unroll
        for (int kb = 0; kb < 4; ++kb) {
          int k0 = kb * 32 + quad * 8;
          f32x4 v0 = *(const f32x4*)(xr + k0);
          f32x4 v1 = *(const f32x4*)(xr + k0 + 4);
#pragma unroll
          for (int e = 0; e < 4; ++e) {
            unsigned short h0 = f2bf(v0[e]);
            ahi[kb][e] = (short)h0;
            alo[kb][e] = (short)f2bf(v0[e] - bf2f(h0));
            unsigned short h1 = f2bf(v1[e]);
            ahi[kb][e + 4] = (short)h1;
            alo[kb][e + 4] = (short)f2bf(v1[e] - bf2f(h1));
          }
        }
#pragma unroll
        for (int nt = 0; nt < 4; ++nt) {
          f32x4 acc0 = {0.f, 0.f, 0.f, 0.f};
          f32x4 acc1 = {0.f, 0.f, 0.f, 0.f};
#pragma unroll
          for (int kb = 0; kb < 4; ++kb) {
            int k0 = kb * 32 + quad * 8;
            short8 bhi = *(const short8*)(x2ht_hi + (nt * 16 + l15) * 136 + k0);
            short8 blo = *(const short8*)(x2ht_lo + (nt * 16 + l15) * 136 + k0);
            acc0 = __builtin_amdgcn_mfma_f32_16x16x32_bf16(ahi[kb], bhi, acc0, 0, 0, 0);
            acc1 = __builtin_amdgcn_mfma_f32_16x16x32_bf16(alo[kb], bhi, acc1, 0, 0, 0);
            acc0 = __builtin_amdgcn_mfma_f32_16x16x32_bf16(ahi[kb], blo, acc0, 0, 0, 0);
          }
          long orow = R0 + mt * 16 + quad * 4;
          int oc = c0 + nt * 16 + l15;
#pragma unroll
          for (int r = 0; r < 4; ++r)
            out[(orow + r) * NHc + oc] = fast_tanh(acc0[r] + acc1[r]);
        }
      }
    }
  }
  // Plain cached stores above need one real release (buffer_wbl2) so other XCDs'
  // u-prefetch loads see them. This is the ONLY fenced barrier in the kernel.
  publish_flag(prolflag, g, 1, tid);

  // ---------------- stage h2h slices into LDS (reuses prologue LDS) ----------------
  unsigned short* hcolT = (unsigned short*)lds;             // [16][520]: h2h[k][J0+jj]
  unsigned short* hrow  = (unsigned short*)(lds + 16640);   // [16][520]: h2h[J0+jj][k]
  unsigned short* bnc   = (unsigned short*)(lds + 33280);   // [64][16] publish bounce
  const int J0 = g * JW;
  for (int i = tid; i < JW * NHc; i += 256) {
    int jj = i & 15, k = i >> 4;
    hcolT[jj * 520 + k] = f2bf(h2h[k * NHc + J0 + jj]);
  }
  for (int i = tid; i < JW * NHc; i += 256) {
    int k = i & 511, jj = i >> 9;
    hrow[jj * 520 + k] = f2bf(h2h[(J0 + jj) * NHc + k]);
  }
  const int jcol = J0 + l15;
  const float b_c = bias[jcol];
  const float gm  = gam_p[jcol];
  const float ep  = eps_p[jcol];
  __syncthreads();
  wait_flags(prolflag, 1, tid);

  // Hoist h2h B-fragments into registers for the whole recurrence (1 wave/SIMD ->
  // VGPR budget 512; +128 VGPRs here kills all per-step ds_reads).
  short8 bc[16], br[16];
#pragma unroll
  for (int kb = 0; kb < 16; ++kb) {
    bc[kb] = *(const short8*)(hcolT + l15 * 520 + kb * 32 + quad * 8);
    br[kb] = *(const short8*)(hrow  + l15 * 520 + kb * 32 + quad * 8);
  }

  // ---------------- recurrent loop ----------------
  const int arow = wv * 16 + l15;       // A-frag row (m = lane&15)
  const int brow = wv * 16 + quad * 4;  // C/D rows (quad*4 + r)
  const int fbase = arow * NHc;         // u16 index base for A-frag loads
  float hy_r[4] = {0.f, 0.f, 0.f, 0.f};
  float hz_r[4] = {0.f, 0.f, 0.f, 0.f};
  float pre_r[4];

  for (int t = 0; t < Tsz; ++t) {
    // prefetch forcing term U[b,t,jcol] (plain cached loads; prologue data)
    float u_r[4];
#pragma unroll
    for (int r = 0; r < 4; ++r)
      u_r[r] = out[((long)(brow + r) * Tsz + t) * NHc + jcol];

    if (t > 0) {
      wait_nf(hyflag, t, tid);   // hy_t published with value t
      const u64_t* hb64 = (const u64_t*)(hybuf + (size_t)(t & 1) * (Bsz * NHc));
      short8 af[16];
#pragma unroll
      for (int kb = 0; kb < 16; ++kb)
        af[kb] = ld_frag(hb64, (fbase + kb * 32 + quad * 8) >> 2);
      f32x4 a0 = {0.f, 0.f, 0.f, 0.f}, a1 = {0.f, 0.f, 0.f, 0.f};
#pragma unroll
      for (int kb = 0; kb < 16; kb += 2) {
        a0 = __builtin_amdgcn_mfma_f32_16x16x32_bf16(af[kb],     bc[kb],     a0, 0, 0, 0);
        a1 = __builtin_amdgcn_mfma_f32_16x16x32_bf16(af[kb + 1], bc[kb + 1], a1, 0, 0, 0);
      }
#pragma unroll
      for (int r = 0; r < 4; ++r) pre_r[r] = fast_tanh(a0[r] + a1[r] + b_c);
    } else {
#pragma unroll
      for (int r = 0; r < 4; ++r) pre_r[r] = fast_tanh(b_c);  // hy_0 = 0
    }

    // publish pre slice (bf16) via LDS bounce + write-through atomics
    unsigned short* pb = prebuf + (size_t)(t & 1) * (Bsz * NHc);
#pragma unroll
    for (int r = 0; r < 4; ++r)
      bnc[(brow + r) * 16 + l15] = f2bf(pre_r[r]);
    publish_nf(pb, bnc, J0, &preflag[g * FLG], t + 1, tid);
    wait_nf(preflag, t + 1, tid);

    // phase 2: C2 = pre @ h2h^T for own columns
    const u64_t* pb64 = (const u64_t*)pb;
    short8 af2[16];
#pragma unroll
    for (int kb = 0; kb < 16; ++kb)
      af2[kb] = ld_frag(pb64, (fbase + kb * 32 + quad * 8) >> 2);
    f32x4 c0v = {0.f, 0.f, 0.f, 0.f}, c1v = {0.f, 0.f, 0.f, 0.f};
#pragma unroll
    for (int kb = 0; kb < 16; kb += 2) {
      c0v = __builtin_amdgcn_mfma_f32_16x16x32_bf16(af2[kb],     br[kb],     c0v, 0, 0, 0);
      c1v = __builtin_amdgcn_mfma_f32_16x16x32_bf16(af2[kb + 1], br[kb + 1], c1v, 0, 0, 0);
    }

    // state update (fp32)
#pragma unroll
    for (int r = 0; r < 4; ++r) {
      float c2 = c0v[r] + c1v[r];
      float hz = hz_r[r] + DTc * (u_r[r] - c2 - gm * hy_r[r] - ep * hz_r[r]);
      hz_r[r] = hz;
      hy_r[r] += DTc * hz;
    }

    if (t + 1 < Tsz) {
      // publish hy FIRST (it gates every other WG's next step), out-store after
      unsigned short* hbw = hybuf + (size_t)((t + 1) & 1) * (Bsz * NHc);
#pragma unroll
      for (int r = 0; r < 4; ++r)
        bnc[(brow + r) * 16 + l15] = f2bf(hy_r[r]);
      publish_nf(hbw, bnc, J0, &hyflag[g * FLG], t + 1, tid);
#pragma unroll
      for (int r = 0; r < 4; ++r)
        out[((long)(brow + r) * Tsz + t) * NHc + jcol] = hy_r[r];
    } else {
#pragma unroll
      for (int r = 0; r < 4; ++r)
        out[((long)(brow + r) * Tsz + t) * NHc + jcol] = hy_r[r];
      // final hy tail
#pragma unroll
      for (int r = 0; r < 4; ++r)
        out[(long)Bsz * Tsz * NHc + (long)(brow + r) * NHc + jcol] = hy_r[r];
    }
  }
}

extern "C" void kernel_launch(void* const* d_in, const int* in_sizes, int n_in,
                              void* d_out, int out_size, void* d_ws, size_t ws_size,
                              hipStream_t stream) {
  const float* x    = (const float*)d_in[0];
  const float* x2h  = (const float*)d_in[1];
  const float* h2h  = (const float*)d_in[2];
  const float* bias = (const float*)d_in[3];
  const float* gam  = (const float*)d_in[4];
  const float* eps  = (const float*)d_in[5];
  (void)in_sizes; (void)n_in; (void)out_size; (void)ws_size;
  pirn_kernel<<<dim3(NWG), dim3(256), 0, stream>>>(
      x, x2h, h2h, bias, gam, eps, (float*)d_out, (char*)d_ws);
}